// Round 3
// baseline (153.344 us; speedup 1.0000x reference)
//
#include <hip/hip_runtime.h>
#include <math.h>

// out[n,d] = sum_k basis(t_n)[k] * W[vid_n, d, k];  V=128, D=64, K=13.
// Single fused kernel: block-local bucket-by-video, weights register-cached
// per (video, lane=d), basis computed once per n in LDS, contiguous stores.

#define V 128
#define D 64
#define K 13
#define CHUNK 1024        // n's per block
#define BS 256            // threads per block
#define PER (CHUNK / BS)  // 4 n's per thread
#define BST 16            // basis row stride in floats (16B-aligned for float4)

__global__ __launch_bounds__(256, 2) void fused_kernel(
    const float* __restrict__ times, const int* __restrict__ ids,
    const float* __restrict__ weights, float* __restrict__ out, int n)
{
    __shared__ float basis[CHUNK * BST];      // 64 KB
    __shared__ unsigned short list[CHUNK];    // 2 KB: bucket-sorted local indices
    __shared__ int cnt[V];                    // per-video count
    __shared__ int start[V];                  // exclusive prefix (group start)
    __shared__ int cur[V];                    // placement cursor

    int tid = threadIdx.x;
    int base = blockIdx.x * CHUNK;

    if (tid < V) cnt[tid] = 0;
    __syncthreads();

    // ---- Phase 1: coalesced loads, per-n basis into LDS, count videos ----
    int myv[PER];
#pragma unroll
    for (int i = 0; i < PER; ++i) {
        int li = i * BS + tid;
        int g = base + li;
        myv[i] = -1;
        if (g < n) {
            float t = times[g];               // coalesced dword
            int v = ids[g];                   // coalesced dword
            myv[i] = v;
            atomicAdd(&cnt[v], 1);
            float s, c;
            __sincosf(3.14159265358979323846f * t, &s, &c);
            float sa[6], ca[6];
            sa[0] = s; ca[0] = c;
#pragma unroll
            for (int j = 1; j < 6; ++j) {     // double-angle: sin/cos(2^j*pi*t)
                sa[j] = 2.0f * sa[j - 1] * ca[j - 1];
                ca[j] = 1.0f - 2.0f * sa[j - 1] * sa[j - 1];
            }
            float4* bp = (float4*)&basis[li * BST];
            bp[0] = make_float4(1.0f, sa[0], sa[1], sa[2]);
            bp[1] = make_float4(sa[3], sa[4], sa[5], ca[0]);
            bp[2] = make_float4(ca[1], ca[2], ca[3], ca[4]);
            basis[li * BST + 12] = ca[5];
        }
    }
    __syncthreads();

    // ---- Exclusive scan of cnt -> start (Hillis-Steele over 128 bins) ----
    if (tid < V) start[tid] = cnt[tid];
    __syncthreads();
    for (int off = 1; off < V; off <<= 1) {
        int val = 0;
        if (tid < V && tid >= off) val = start[tid - off];
        __syncthreads();
        if (tid < V) start[tid] += val;
        __syncthreads();
    }
    if (tid < V) { start[tid] -= cnt[tid]; cur[tid] = 0; }  // inclusive -> exclusive
    __syncthreads();

    // ---- Place local indices into per-video groups (order within group arbitrary) ----
#pragma unroll
    for (int i = 0; i < PER; ++i) {
        if (myv[i] >= 0) {
            int r = atomicAdd(&cur[myv[i]], 1);
            list[start[myv[i]] + r] = (unsigned short)(i * BS + tid);
        }
    }
    __syncthreads();

    // ---- Phase 2: wave = 64 lanes = 64 d's; each wave handles videos v%4==wave ----
    int wave = tid >> 6;
    int lane = tid & 63;
    for (int v = wave; v < V; v += 4) {
        int c = cnt[v];                       // LDS broadcast (wave-uniform value)
        if (c == 0) continue;
        int s0 = start[v];
        // weights row for (v, d=lane): 13 floats, 52B stride -> only 4B aligned,
        // so scalar dword loads (once per group, L2-resident after first block).
        const float* wp = weights + (v * D + lane) * K;
        float w0 = wp[0], w1 = wp[1], w2 = wp[2], w3 = wp[3];
        float w4 = wp[4], w5 = wp[5], w6 = wp[6], w7 = wp[7];
        float w8 = wp[8], w9 = wp[9], w10 = wp[10], w11 = wp[11], w12 = wp[12];
        for (int j = 0; j < c; ++j) {         // iterations independent -> pipelines
            int li = list[s0 + j];            // broadcast u16 read
            const float4* bp = (const float4*)&basis[li * BST];
            float4 b0 = bp[0], b1 = bp[1], b2 = bp[2];
            float b12 = basis[li * BST + 12];
            float acc = ((b0.x * w0 + b0.y * w1) + (b0.z * w2 + b0.w * w3))
                      + ((b1.x * w4 + b1.y * w5) + (b1.z * w6 + b1.w * w7))
                      + (((b2.x * w8 + b2.y * w9) + (b2.z * w10 + b2.w * w11))
                         + b12 * w12);
            out[(long)(base + li) * D + lane] = acc;  // 256B contiguous per wave
        }
    }
}

extern "C" void kernel_launch(void* const* d_in, const int* in_sizes, int n_in,
                              void* d_out, int out_size, void* d_ws, size_t ws_size,
                              hipStream_t stream) {
    const float* times = (const float*)d_in[0];
    const int* ids = (const int*)d_in[1];
    const float* weights = (const float*)d_in[2];
    float* out = (float*)d_out;
    int n = in_sizes[0];

    int nblk = (n + CHUNK - 1) / CHUNK;   // 391 blocks @ n=400000: all co-resident (2/CU)
    fused_kernel<<<nblk, BS, 0, stream>>>(times, ids, weights, out, n);
}